// Round 1
// baseline (128.596 us; speedup 1.0000x reference)
//
#include <hip/hip_runtime.h>
#include <math.h>

#define EPS_F 1e-8f

__launch_bounds__(256)
__global__ void iou3d_loss_kernel(const float* __restrict__ g,
                                  const float* __restrict__ q,
                                  float* __restrict__ partial,
                                  int n) {
    const int gid = blockIdx.x * blockDim.x + threadIdx.x;
    float loss = 0.0f;
    if (gid < n) {
        const float* gb = g + (size_t)gid * 7;
        const float* qb = q + (size_t)gid * 7;
        const float gx = gb[0], gy = gb[1], gz = gb[2], gh = gb[3], gw = gb[4], gl = gb[5], gr = gb[6];
        const float qx = qb[0], qy = qb[1], qz = qb[2], qh = qb[3], qw = qb[4], ql = qb[5], qr = qb[6];

        float sg, cg, sq_, cq;
        sincosf(gr, &sg, &cg);
        sincosf(qr, &sq_, &cq);

        // BEV corners (x,z plane): cx = LX*l, cz = LZ*w; X = c*cx + s*cz + x; Z = -s*cx + c*cz + z
        const float LX[4] = {0.5f, 0.5f, -0.5f, -0.5f};
        const float LZ[4] = {0.5f, -0.5f, -0.5f, 0.5f};
        float axv[4], azv[4], bxv[4], bzv[4];
#pragma unroll
        for (int k = 0; k < 4; ++k) {
            const float cxg = LX[k] * gl, czg = LZ[k] * gw;
            axv[k] =  cg * cxg + sg * czg + gx;
            azv[k] = -sg * cxg + cg * czg + gz;
            const float cxq = LX[k] * ql, czq = LZ[k] * qw;
            bxv[k] =  cq * cxq + sq_ * czq + qx;
            bzv[k] = -sq_ * cxq + cq * czq + qz;
        }

        // 16 edge-edge intersection candidates + 8 corners = 24 points
        float ptx[24], ptz[24];
        bool ok[24];
#pragma unroll
        for (int ii = 0; ii < 4; ++ii) {
            const float a1x = axv[ii], a1z = azv[ii];
            const float d1x = axv[(ii + 1) & 3] - a1x;
            const float d1z = azv[(ii + 1) & 3] - a1z;
#pragma unroll
            for (int jj = 0; jj < 4; ++jj) {
                const float b1x = bxv[jj], b1z = bzv[jj];
                const float d2x = bxv[(jj + 1) & 3] - b1x;
                const float d2z = bzv[(jj + 1) & 3] - b1z;
                const float denom = d1x * d2z - d1z * d2x;       // cross(d1, d2)
                const bool nz = fabsf(denom) > EPS_F;
                const float safe = nz ? denom : 1.0f;
                const float ex = b1x - a1x, ez = b1z - a1z;       // b1 - a1
                const float t = (ex * d2z - ez * d2x) / safe;     // cross(e, d2)/safe
                const float u = (ex * d1z - ez * d1x) / safe;     // cross(e, d1)/safe
                const int id = ii * 4 + jj;
                ok[id]  = nz && (t >= 0.0f) && (t <= 1.0f) && (u >= 0.0f) && (u <= 1.0f);
                ptx[id] = a1x + t * d1x;
                ptz[id] = a1z + t * d1z;
            }
        }
        // corners of A inside B, corners of B inside A
#pragma unroll
        for (int k = 0; k < 4; ++k) {
            ptx[16 + k] = axv[k]; ptz[16 + k] = azv[k];
            const float rx = axv[k] - qx, rz = azv[k] - qz;
            const float lx = cq * rx - sq_ * rz;
            const float lz = sq_ * rx + cq * rz;
            ok[16 + k] = (fabsf(lx) <= 0.5f * ql + 1e-5f) && (fabsf(lz) <= 0.5f * qw + 1e-5f);

            ptx[20 + k] = bxv[k]; ptz[20 + k] = bzv[k];
            const float rx2 = bxv[k] - gx, rz2 = bzv[k] - gz;
            const float lx2 = cg * rx2 - sg * rz2;
            const float lz2 = sg * rx2 + cg * rz2;
            ok[20 + k] = (fabsf(lx2) <= 0.5f * gl + 1e-5f) && (fabsf(lz2) <= 0.5f * gw + 1e-5f);
        }

        // centroid of valid points (cnt clamped to >=1, matching reference)
        float sx = 0.f, sz = 0.f, cnt = 0.f;
#pragma unroll
        for (int k = 0; k < 24; ++k) {
            if (ok[k]) { sx += ptx[k]; sz += ptz[k]; cnt += 1.f; }
        }
        const float inv = 1.0f / fmaxf(cnt, 1.0f);
        const float mx = sx * inv, mz = sz * inv;

        float ang[24];
#pragma unroll
        for (int k = 0; k < 24; ++k) {
            ang[k] = ok[k] ? atan2f(ptz[k] - mz, ptx[k] - mx) : 1e9f;
        }

        // wraparound target: valid point with min (ang, idx) key
        float ma = 1e30f, mwx = 0.f, mwz = 0.f;
#pragma unroll
        for (int j = 0; j < 24; ++j) {
            if (ok[j] && (ang[j] < ma)) { ma = ang[j]; mwx = ptx[j]; mwz = ptz[j]; }
        }

        // shoelace over valid points in stable-(ang,idx)-sorted cyclic order,
        // via successor search (identical traversal to jnp.argsort-stable)
        float area2 = 0.f;
#pragma unroll
        for (int i2 = 0; i2 < 24; ++i2) {
            const float ai = ang[i2];
            float sa = 1e30f, sxx = mwx, szz = mwz;
#pragma unroll
            for (int j = 0; j < 24; ++j) {
                const bool cand = ok[j] && ((ang[j] > ai) || ((ang[j] == ai) && (j > i2)));
                if (cand && (ang[j] < sa)) { sa = ang[j]; sxx = ptx[j]; szz = ptz[j]; }
            }
            if (ok[i2]) area2 += ptx[i2] * szz - ptz[i2] * sxx;
        }
        const float area = 0.5f * fabsf(area2);

        const float hov = fmaxf(fminf(gy, qy) - fmaxf(gy - gh, qy - qh), 0.0f);
        const float inter = area * hov;
        const float va = gh * gw * gl;
        const float vb = qh * qw * ql;
        float iou = inter / (va + vb - inter + EPS_F);
        iou = fminf(fmaxf(iou, 0.0f), 1.0f);
        loss = 1.0f - iou;
    }

    // deterministic block reduction: wave shfl (width 64) + LDS
#pragma unroll
    for (int off = 32; off > 0; off >>= 1) loss += __shfl_down(loss, off, 64);
    __shared__ float wsum[4];
    const int lane = threadIdx.x & 63;
    const int wid = threadIdx.x >> 6;
    if (lane == 0) wsum[wid] = loss;
    __syncthreads();
    if (threadIdx.x == 0) {
        partial[blockIdx.x] = wsum[0] + wsum[1] + wsum[2] + wsum[3];
    }
}

__launch_bounds__(256)
__global__ void final_reduce_kernel(const float* __restrict__ partial,
                                    float* __restrict__ out,
                                    int nblocks, float invn) {
    float s = 0.f;
    for (int k = threadIdx.x; k < nblocks; k += 256) s += partial[k];
#pragma unroll
    for (int off = 32; off > 0; off >>= 1) s += __shfl_down(s, off, 64);
    __shared__ float wsum[4];
    const int lane = threadIdx.x & 63;
    const int wid = threadIdx.x >> 6;
    if (lane == 0) wsum[wid] = s;
    __syncthreads();
    if (threadIdx.x == 0) out[0] = (wsum[0] + wsum[1] + wsum[2] + wsum[3]) * invn;
}

extern "C" void kernel_launch(void* const* d_in, const int* in_sizes, int n_in,
                              void* d_out, int out_size, void* d_ws, size_t ws_size,
                              hipStream_t stream) {
    const float* g = (const float*)d_in[0];
    const float* q = (const float*)d_in[1];
    float* out = (float*)d_out;
    const int n = in_sizes[0] / 7;
    const int block = 256;
    const int nblocks = (n + block - 1) / block;   // 2048 for N=524288
    float* partial = (float*)d_ws;                 // 2048 floats = 8 KB scratch
    iou3d_loss_kernel<<<nblocks, block, 0, stream>>>(g, q, partial, n);
    final_reduce_kernel<<<1, block, 0, stream>>>(partial, out, nblocks, 1.0f / (float)n);
}

// Round 2
// 65.091 us; speedup vs baseline: 1.9756x; 1.9756x over previous
//
#include <hip/hip_runtime.h>
#include <math.h>

#define EPS_F 1e-8f
#define BIGK  1e9f
#define PADK  2e9f

__launch_bounds__(256)
__global__ void iou3d_loss_kernel(const float* __restrict__ g,
                                  const float* __restrict__ q,
                                  float* __restrict__ partial,
                                  int n) {
    const int gid = blockIdx.x * blockDim.x + threadIdx.x;
    float loss = 0.0f;
    if (gid < n) {
        const float* gb = g + (size_t)gid * 7;
        const float* qb = q + (size_t)gid * 7;
        const float gx = gb[0], gy = gb[1], gz = gb[2], gh = gb[3], gw = gb[4], gl = gb[5], gr = gb[6];
        const float qx = qb[0], qy = qb[1], qz = qb[2], qh = qb[3], qw = qb[4], ql = qb[5], qr = qb[6];

        float sg, cg, sq_, cq;
        __sincosf(gr, &sg, &cg);
        __sincosf(qr, &sq_, &cq);

        // BEV corners: cx = LX*l, cz = LZ*w; X = c*cx + s*cz + x; Z = -s*cx + c*cz + z
        const float LX[4] = {0.5f, 0.5f, -0.5f, -0.5f};
        const float LZ[4] = {0.5f, -0.5f, -0.5f, 0.5f};
        float axv[4], azv[4], bxv[4], bzv[4];
#pragma unroll
        for (int k = 0; k < 4; ++k) {
            const float cxg = LX[k] * gl, czg = LZ[k] * gw;
            axv[k] =  cg * cxg + sg * czg + gx;
            azv[k] = -sg * cxg + cg * czg + gz;
            const float cxq = LX[k] * ql, czq = LZ[k] * qw;
            bxv[k] =  cq * cxq + sq_ * czq + qx;
            bzv[k] = -sq_ * cxq + cq * czq + qz;
        }

        // 24 candidate points (16 edge-edge intersections + 8 corners), valid mask packed
        float px[32], pz[32], key[32];
        unsigned okm = 0u;
#pragma unroll
        for (int ii = 0; ii < 4; ++ii) {
            const float a1x = axv[ii], a1z = azv[ii];
            const float d1x = axv[(ii + 1) & 3] - a1x;
            const float d1z = azv[(ii + 1) & 3] - a1z;
#pragma unroll
            for (int jj = 0; jj < 4; ++jj) {
                const float b1x = bxv[jj], b1z = bzv[jj];
                const float d2x = bxv[(jj + 1) & 3] - b1x;
                const float d2z = bzv[(jj + 1) & 3] - b1z;
                const float denom = d1x * d2z - d1z * d2x;
                const bool nz = fabsf(denom) > EPS_F;
                const float safe = nz ? denom : 1.0f;
                const float ex = b1x - a1x, ez = b1z - a1z;
                const float t = __fdividef(ex * d2z - ez * d2x, safe);
                const float u = __fdividef(ex * d1z - ez * d1x, safe);
                const int id = ii * 4 + jj;
                const bool ok = nz && (t >= 0.0f) && (t <= 1.0f) && (u >= 0.0f) && (u <= 1.0f);
                okm |= (unsigned)ok << id;
                px[id] = a1x + t * d1x;
                pz[id] = a1z + t * d1z;
            }
        }
#pragma unroll
        for (int k = 0; k < 4; ++k) {
            px[16 + k] = axv[k]; pz[16 + k] = azv[k];
            const float rx = axv[k] - qx, rz = azv[k] - qz;
            const float lx = cq * rx - sq_ * rz;
            const float lz = sq_ * rx + cq * rz;
            const bool okA = (fabsf(lx) <= 0.5f * ql + 1e-5f) && (fabsf(lz) <= 0.5f * qw + 1e-5f);
            okm |= (unsigned)okA << (16 + k);

            px[20 + k] = bxv[k]; pz[20 + k] = bzv[k];
            const float rx2 = bxv[k] - gx, rz2 = bzv[k] - gz;
            const float lx2 = cg * rx2 - sg * rz2;
            const float lz2 = sg * rx2 + cg * rz2;
            const bool okB = (fabsf(lx2) <= 0.5f * gl + 1e-5f) && (fabsf(lz2) <= 0.5f * gw + 1e-5f);
            okm |= (unsigned)okB << (20 + k);
        }

        // centroid of valid points (cnt clamped >=1, matching reference)
        float sx = 0.f, sz = 0.f, cnt = 0.f;
#pragma unroll
        for (int k = 0; k < 24; ++k) {
            const bool v = (okm >> k) & 1u;
            sx += v ? px[k] : 0.f;
            sz += v ? pz[k] : 0.f;
            cnt += v ? 1.f : 0.f;
        }
        const float invc = 1.0f / fmaxf(cnt, 1.0f);
        const float mx = sx * invc, mz = sz * invc;

        // diamond pseudo-angle: strictly monotone in atan2(rz, rx) -> same sort order
        // range (-2, 2]; invalid -> 1e9 (before pads at 2e9)
#pragma unroll
        for (int k = 0; k < 24; ++k) {
            const bool v = (okm >> k) & 1u;
            const float rx = px[k] - mx, rz = pz[k] - mz;
            const float dd = fabsf(rx) + fabsf(rz);
            const float t = __fdividef(rz, dd + 1e-30f);
            const float pa = (rx >= 0.0f) ? t : (copysignf(2.0f, rz) - t);
            key[k] = v ? pa : BIGK;
        }
#pragma unroll
        for (int k = 24; k < 32; ++k) { key[k] = PADK; px[k] = 0.f; pz[k] = 0.f; }

        // bitonic sort-32 ascending on (key, px, pz) — all static indices, 16 indep CEs/pass
#pragma unroll
        for (int kk = 2; kk <= 32; kk <<= 1) {
#pragma unroll
            for (int jj = kk >> 1; jj > 0; jj >>= 1) {
#pragma unroll
                for (int i = 0; i < 32; ++i) {
                    const int l = i ^ jj;
                    if (l > i) {
                        const bool up = ((i & kk) == 0);
                        const float ka = key[i], kb = key[l];
                        const float xa = px[i],  xb = px[l];
                        const float za = pz[i],  zb = pz[l];
                        const bool sw = up ? (ka > kb) : (ka < kb);
                        key[i] = sw ? kb : ka;  key[l] = sw ? ka : kb;
                        px[i]  = sw ? xb : xa;  px[l]  = sw ? xa : xb;
                        pz[i]  = sw ? zb : za;  pz[l]  = sw ? za : zb;
                    }
                }
            }
        }

        // slots 0..23 are now the reference's stable-sorted 24 points (pads sorted to 24..31).
        // Reference trick: invalid points take the first sorted point's coords -> their
        // shoelace terms telescope to the wraparound edge.
        const float p0x = px[0], p0z = pz[0];
#pragma unroll
        for (int i = 0; i < 24; ++i) {
            const bool inval = key[i] >= BIGK;
            px[i] = inval ? p0x : px[i];
            pz[i] = inval ? p0z : pz[i];
        }
        float area2 = 0.f;
#pragma unroll
        for (int i = 0; i < 24; ++i) {
            const int j2 = (i + 1) % 24;
            area2 += px[i] * pz[j2] - pz[i] * px[j2];
        }
        const float area = 0.5f * fabsf(area2);

        const float hov = fmaxf(fminf(gy, qy) - fmaxf(gy - gh, qy - qh), 0.0f);
        const float inter = area * hov;
        const float va = gh * gw * gl;
        const float vb = qh * qw * ql;
        float iou = inter / (va + vb - inter + EPS_F);
        iou = fminf(fmaxf(iou, 0.0f), 1.0f);
        loss = 1.0f - iou;
    }

    // deterministic block reduction: wave shfl (width 64) + LDS
#pragma unroll
    for (int off = 32; off > 0; off >>= 1) loss += __shfl_down(loss, off, 64);
    __shared__ float wsum[4];
    const int lane = threadIdx.x & 63;
    const int wid = threadIdx.x >> 6;
    if (lane == 0) wsum[wid] = loss;
    __syncthreads();
    if (threadIdx.x == 0) {
        partial[blockIdx.x] = wsum[0] + wsum[1] + wsum[2] + wsum[3];
    }
}

__launch_bounds__(256)
__global__ void final_reduce_kernel(const float* __restrict__ partial,
                                    float* __restrict__ out,
                                    int nblocks, float invn) {
    float s = 0.f;
    for (int k = threadIdx.x; k < nblocks; k += 256) s += partial[k];
#pragma unroll
    for (int off = 32; off > 0; off >>= 1) s += __shfl_down(s, off, 64);
    __shared__ float wsum[4];
    const int lane = threadIdx.x & 63;
    const int wid = threadIdx.x >> 6;
    if (lane == 0) wsum[wid] = s;
    __syncthreads();
    if (threadIdx.x == 0) out[0] = (wsum[0] + wsum[1] + wsum[2] + wsum[3]) * invn;
}

extern "C" void kernel_launch(void* const* d_in, const int* in_sizes, int n_in,
                              void* d_out, int out_size, void* d_ws, size_t ws_size,
                              hipStream_t stream) {
    const float* g = (const float*)d_in[0];
    const float* q = (const float*)d_in[1];
    float* out = (float*)d_out;
    const int n = in_sizes[0] / 7;
    const int block = 256;
    const int nblocks = (n + block - 1) / block;   // 2048 for N=524288
    float* partial = (float*)d_ws;                 // 2048 floats = 8 KB scratch
    iou3d_loss_kernel<<<nblocks, block, 0, stream>>>(g, q, partial, n);
    final_reduce_kernel<<<1, block, 0, stream>>>(partial, out, nblocks, 1.0f / (float)n);
}

// Round 3
// 37.239 us; speedup vs baseline: 3.4532x; 1.7479x over previous
//
#include <hip/hip_runtime.h>
#include <math.h>

#define EPS_F 1e-8f
#define INVALID_KEY 0xFFFFFF00u
#define PAD_KEY     0xFFFFFFFFu
#define VALID_THRESH 0xF0000000u

__launch_bounds__(256)
__global__ void iou3d_loss_kernel(const float* __restrict__ g,
                                  const float* __restrict__ q,
                                  float* __restrict__ partial,
                                  int n) {
    // per-thread 24-slot point store; stride 25 dwords -> gcd(25,32)=1, conflict-free static access
    __shared__ float pxl[256 * 25];
    __shared__ float pzl[256 * 25];
    float* mypx = pxl + threadIdx.x * 25;
    float* mypz = pzl + threadIdx.x * 25;

    const int gid = blockIdx.x * blockDim.x + threadIdx.x;
    float loss = 0.0f;
    if (gid < n) {
        const float* gb = g + (size_t)gid * 7;
        const float* qb = q + (size_t)gid * 7;
        const float gx = gb[0], gy = gb[1], gz = gb[2], gh = gb[3], gw = gb[4], gl = gb[5], gr = gb[6];
        const float qx = qb[0], qy = qb[1], qz = qb[2], qh = qb[3], qw = qb[4], ql = qb[5], qr = qb[6];

        float sg, cg, sq_, cq;
        __sincosf(gr, &sg, &cg);
        __sincosf(qr, &sq_, &cq);

        // BEV corners: cx = LX*l, cz = LZ*w; X = c*cx + s*cz + x; Z = -s*cx + c*cz + z
        const float LX[4] = {0.5f, 0.5f, -0.5f, -0.5f};
        const float LZ[4] = {0.5f, -0.5f, -0.5f, 0.5f};
        float axv[4], azv[4], bxv[4], bzv[4];
#pragma unroll
        for (int k = 0; k < 4; ++k) {
            const float cxg = LX[k] * gl, czg = LZ[k] * gw;
            axv[k] =  cg * cxg + sg * czg + gx;
            azv[k] = -sg * cxg + cg * czg + gz;
            const float cxq = LX[k] * ql, czq = LZ[k] * qw;
            bxv[k] =  cq * cxq + sq_ * czq + qx;
            bzv[k] = -sq_ * cxq + cq * czq + qz;
        }

        // 24 candidate points: 16 edge-edge intersections + 8 corners
        float px[24], pz[24];
        unsigned okm = 0u;
#pragma unroll
        for (int ii = 0; ii < 4; ++ii) {
            const float a1x = axv[ii], a1z = azv[ii];
            const float d1x = axv[(ii + 1) & 3] - a1x;
            const float d1z = azv[(ii + 1) & 3] - a1z;
#pragma unroll
            for (int jj = 0; jj < 4; ++jj) {
                const float b1x = bxv[jj], b1z = bzv[jj];
                const float d2x = bxv[(jj + 1) & 3] - b1x;
                const float d2z = bzv[(jj + 1) & 3] - b1z;
                const float denom = d1x * d2z - d1z * d2x;
                const bool nz = fabsf(denom) > EPS_F;
                const float safe = nz ? denom : 1.0f;
                const float rs = __frcp_rn(safe);                 // one rcp shared by t and u
                const float ex = b1x - a1x, ez = b1z - a1z;
                const float t = (ex * d2z - ez * d2x) * rs;
                const float u = (ex * d1z - ez * d1x) * rs;
                const int id = ii * 4 + jj;
                const bool ok = nz && (t >= 0.0f) && (t <= 1.0f) && (u >= 0.0f) && (u <= 1.0f);
                okm |= (unsigned)ok << id;
                px[id] = a1x + t * d1x;
                pz[id] = a1z + t * d1z;
            }
        }
#pragma unroll
        for (int k = 0; k < 4; ++k) {
            px[16 + k] = axv[k]; pz[16 + k] = azv[k];
            const float rx = axv[k] - qx, rz = azv[k] - qz;
            const float lx = cq * rx - sq_ * rz;
            const float lz = sq_ * rx + cq * rz;
            const bool okA = (fabsf(lx) <= 0.5f * ql + 1e-5f) && (fabsf(lz) <= 0.5f * qw + 1e-5f);
            okm |= (unsigned)okA << (16 + k);

            px[20 + k] = bxv[k]; pz[20 + k] = bzv[k];
            const float rx2 = bxv[k] - gx, rz2 = bzv[k] - gz;
            const float lx2 = cg * rx2 - sg * rz2;
            const float lz2 = sg * rx2 + cg * rz2;
            const bool okB = (fabsf(lx2) <= 0.5f * gl + 1e-5f) && (fabsf(lz2) <= 0.5f * gw + 1e-5f);
            okm |= (unsigned)okB << (20 + k);
        }

        // centroid of valid points (cnt clamped >=1, matching reference)
        float sx = 0.f, sz = 0.f, cnt = 0.f;
#pragma unroll
        for (int k = 0; k < 24; ++k) {
            const bool v = (okm >> k) & 1u;
            sx += v ? px[k] : 0.f;
            sz += v ? pz[k] : 0.f;
            cnt += v ? 1.f : 0.f;
        }
        const float invc = __frcp_rn(fmaxf(cnt, 1.0f));
        const float mx = sx * invc, mz = sz * invc;

        // stash points in LDS (static offsets, conflict-free), build sortable u32 keys
        unsigned key[32];
#pragma unroll
        for (int k = 0; k < 24; ++k) {
            mypx[k] = px[k];
            mypz[k] = pz[k];
            const bool v = (okm >> k) & 1u;
            // diamond pseudo-angle, strictly monotone in atan2(rz, rx)
            const float rx = px[k] - mx, rz = pz[k] - mz;
            const float dd = fabsf(rx) + fabsf(rz);
            const float t = rz * __frcp_rn(dd + 1e-30f);
            const float pa = (rx >= 0.0f) ? t : (copysignf(2.0f, rz) - t);
            // order-preserving float->u32, low 5 bits replaced by index (stable tie-break)
            const unsigned u = __float_as_uint(pa);
            const unsigned s = ((int)u < 0) ? ~u : (u | 0x80000000u);
            key[k] = v ? ((s & ~31u) | (unsigned)k) : (INVALID_KEY | (unsigned)k);
        }
#pragma unroll
        for (int k = 24; k < 32; ++k) key[k] = PAD_KEY;

        // bitonic sort-32 ascending on u32 keys: CE = v_min_u32 + v_max_u32 (dir compile-time)
#pragma unroll
        for (int kk = 2; kk <= 32; kk <<= 1) {
#pragma unroll
            for (int jj = kk >> 1; jj > 0; jj >>= 1) {
#pragma unroll
                for (int i = 0; i < 32; ++i) {
                    const int l = i ^ jj;
                    if (l > i) {
                        const unsigned a = key[i], b = key[l];
                        const unsigned lo = (a < b) ? a : b;
                        const unsigned hi = (a < b) ? b : a;
                        if ((i & kk) == 0) { key[i] = lo; key[l] = hi; }
                        else               { key[i] = hi; key[l] = lo; }
                    }
                }
            }
        }

        // gather in sorted order; invalid slots (sorted to the tail) take slot-0's point,
        // telescoping the shoelace exactly like the reference's where(mask, pts, pts[0])
        float qxx[24], qzz[24];
#pragma unroll
        for (int i = 0; i < 24; ++i) {
            const unsigned ki = key[i];
            const unsigned idx = ki & 31u;
            qxx[i] = mypx[idx];              // runtime ds_read (own region)
            qzz[i] = mypz[idx];
        }
        const float p0x = qxx[0], p0z = qzz[0];
#pragma unroll
        for (int i = 0; i < 24; ++i) {
            const bool val = key[i] < VALID_THRESH;
            qxx[i] = val ? qxx[i] : p0x;
            qzz[i] = val ? qzz[i] : p0z;
        }
        float area2 = 0.f;
#pragma unroll
        for (int i = 0; i < 24; ++i) {
            const int j2 = (i + 1) % 24;
            area2 += qxx[i] * qzz[j2] - qzz[i] * qxx[j2];
        }
        const float area = 0.5f * fabsf(area2);

        const float hov = fmaxf(fminf(gy, qy) - fmaxf(gy - gh, qy - qh), 0.0f);
        const float inter = area * hov;
        const float va = gh * gw * gl;
        const float vb = qh * qw * ql;
        float iou = inter / (va + vb - inter + EPS_F);
        iou = fminf(fmaxf(iou, 0.0f), 1.0f);
        loss = 1.0f - iou;
    }

    // deterministic block reduction: wave shfl (width 64) + LDS
#pragma unroll
    for (int off = 32; off > 0; off >>= 1) loss += __shfl_down(loss, off, 64);
    __shared__ float wsum[4];
    const int lane = threadIdx.x & 63;
    const int wid = threadIdx.x >> 6;
    if (lane == 0) wsum[wid] = loss;
    __syncthreads();
    if (threadIdx.x == 0) {
        partial[blockIdx.x] = wsum[0] + wsum[1] + wsum[2] + wsum[3];
    }
}

__launch_bounds__(256)
__global__ void final_reduce_kernel(const float* __restrict__ partial,
                                    float* __restrict__ out,
                                    int nblocks, float invn) {
    float s = 0.f;
    for (int k = threadIdx.x; k < nblocks; k += 256) s += partial[k];
#pragma unroll
    for (int off = 32; off > 0; off >>= 1) s += __shfl_down(s, off, 64);
    __shared__ float wsum[4];
    const int lane = threadIdx.x & 63;
    const int wid = threadIdx.x >> 6;
    if (lane == 0) wsum[wid] = s;
    __syncthreads();
    if (threadIdx.x == 0) out[0] = (wsum[0] + wsum[1] + wsum[2] + wsum[3]) * invn;
}

extern "C" void kernel_launch(void* const* d_in, const int* in_sizes, int n_in,
                              void* d_out, int out_size, void* d_ws, size_t ws_size,
                              hipStream_t stream) {
    const float* g = (const float*)d_in[0];
    const float* q = (const float*)d_in[1];
    float* out = (float*)d_out;
    const int n = in_sizes[0] / 7;
    const int block = 256;
    const int nblocks = (n + block - 1) / block;   // 2048 for N=524288
    float* partial = (float*)d_ws;                 // 2048 floats = 8 KB scratch
    iou3d_loss_kernel<<<nblocks, block, 0, stream>>>(g, q, partial, n);
    final_reduce_kernel<<<1, block, 0, stream>>>(partial, out, nblocks, 1.0f / (float)n);
}

// Round 4
// 36.158 us; speedup vs baseline: 3.5565x; 1.0299x over previous
//
#include <hip/hip_runtime.h>
#include <math.h>

#define EPS_F 1e-8f
#define INVALID_BASE 0xFFFFFF00u
#define PAD_KEY      0xFFFFFFFFu
#define VALID_THRESH 0xF0000000u

__launch_bounds__(256)
__global__ void iou3d_loss_kernel(const float* __restrict__ g,
                                  const float* __restrict__ q,
                                  float* __restrict__ partial,
                                  int n) {
    // compacted per-thread point store: <=16 valid points + 1 pad slot.
    // stride 17 float2 (136 B) -> bases spread across banks; total 34816 B -> 4 blocks/CU
    __shared__ float2 pts[256 * 17];
    float2* myp = pts + threadIdx.x * 17;

    const int gid = blockIdx.x * blockDim.x + threadIdx.x;
    float loss = 0.0f;
    if (gid < n) {
        const float* gb = g + (size_t)gid * 7;
        const float* qb = q + (size_t)gid * 7;
        const float gx = gb[0], gy = gb[1], gz = gb[2], gh = gb[3], gw = gb[4], gl = gb[5], gr = gb[6];
        const float qx = qb[0], qy = qb[1], qz = qb[2], qh = qb[3], qw = qb[4], ql = qb[5], qr = qb[6];

        float sg, cg, sq_, cq;
        __sincosf(gr, &sg, &cg);
        __sincosf(qr, &sq_, &cq);

        // BEV corners: cx = LX*l, cz = LZ*w; X = c*cx + s*cz + x; Z = -s*cx + c*cz + z
        const float LX[4] = {0.5f, 0.5f, -0.5f, -0.5f};
        const float LZ[4] = {0.5f, -0.5f, -0.5f, 0.5f};
        float axv[4], azv[4], bxv[4], bzv[4];
#pragma unroll
        for (int k = 0; k < 4; ++k) {
            const float cxg = LX[k] * gl, czg = LZ[k] * gw;
            axv[k] =  cg * cxg + sg * czg + gx;
            azv[k] = -sg * cxg + cg * czg + gz;
            const float cxq = LX[k] * ql, czq = LZ[k] * qw;
            bxv[k] =  cq * cxq + sq_ * czq + qx;
            bzv[k] = -sq_ * cxq + cq * czq + qz;
        }

        // 24 candidate points: 16 edge-edge intersections + 8 corners
        float px[24], pz[24];
        unsigned okm = 0u;
#pragma unroll
        for (int ii = 0; ii < 4; ++ii) {
            const float a1x = axv[ii], a1z = azv[ii];
            const float d1x = axv[(ii + 1) & 3] - a1x;
            const float d1z = azv[(ii + 1) & 3] - a1z;
#pragma unroll
            for (int jj = 0; jj < 4; ++jj) {
                const float b1x = bxv[jj], b1z = bzv[jj];
                const float d2x = bxv[(jj + 1) & 3] - b1x;
                const float d2z = bzv[(jj + 1) & 3] - b1z;
                const float denom = d1x * d2z - d1z * d2x;
                const bool nz = fabsf(denom) > EPS_F;
                const float safe = nz ? denom : 1.0f;
                const float rs = __frcp_rn(safe);                 // one rcp shared by t and u
                const float ex = b1x - a1x, ez = b1z - a1z;
                const float t = (ex * d2z - ez * d2x) * rs;
                const float u = (ex * d1z - ez * d1x) * rs;
                const int id = ii * 4 + jj;
                const bool ok = nz && (t >= 0.0f) && (t <= 1.0f) && (u >= 0.0f) && (u <= 1.0f);
                okm |= (unsigned)ok << id;
                px[id] = a1x + t * d1x;
                pz[id] = a1z + t * d1z;
            }
        }
#pragma unroll
        for (int k = 0; k < 4; ++k) {
            px[16 + k] = axv[k]; pz[16 + k] = azv[k];
            const float rx = axv[k] - qx, rz = azv[k] - qz;
            const float lx = cq * rx - sq_ * rz;
            const float lz = sq_ * rx + cq * rz;
            const bool okA = (fabsf(lx) <= 0.5f * ql + 1e-5f) && (fabsf(lz) <= 0.5f * qw + 1e-5f);
            okm |= (unsigned)okA << (16 + k);

            px[20 + k] = bxv[k]; pz[20 + k] = bzv[k];
            const float rx2 = bxv[k] - gx, rz2 = bzv[k] - gz;
            const float lx2 = cg * rx2 - sg * rz2;
            const float lz2 = sg * rx2 + cg * rz2;
            const bool okB = (fabsf(lx2) <= 0.5f * gl + 1e-5f) && (fabsf(lz2) <= 0.5f * gw + 1e-5f);
            okm |= (unsigned)okB << (20 + k);
        }

        // centroid of valid points (cnt clamped >=1, matching reference)
        float sx = 0.f, sz = 0.f, cnt = 0.f;
#pragma unroll
        for (int k = 0; k < 24; ++k) {
            const bool v = (okm >> k) & 1u;
            sx += v ? px[k] : 0.f;
            sz += v ? pz[k] : 0.f;
            cnt += v ? 1.f : 0.f;
        }
        const float invc = __frcp_rn(fmaxf(cnt, 1.0f));
        const float mx = sx * invc, mz = sz * invc;

        // keys + compacted LDS writes. Low 5 bits = compact slot c (monotone in k among
        // valid -> identical stable order to the reference's index tie-break).
        myp[0] = make_float2(0.f, 0.f);     // defined data for the cnt==0 case
        unsigned key[32];
        unsigned c = 0u;
#pragma unroll
        for (int k = 0; k < 24; ++k) {
            const bool v = (okm >> k) & 1u;
            // diamond pseudo-angle, strictly monotone in atan2(rz, rx)
            const float rx = px[k] - mx, rz = pz[k] - mz;
            const float dd = fabsf(rx) + fabsf(rz);
            const float t = rz * __frcp_rn(dd + 1e-30f);
            const float pa = (rx >= 0.0f) ? t : (copysignf(2.0f, rz) - t);
            // order-preserving float->u32, low 5 bits replaced by compact slot
            const unsigned u = __float_as_uint(pa);
            const unsigned s = ((int)u < 0) ? ~u : (u | 0x80000000u);
            const unsigned cw = (c > 16u) ? 16u : c;   // pathological >16-valid clamp
            key[k] = v ? ((s & ~31u) | cw) : (INVALID_BASE | cw);
            if (v) myp[cw] = make_float2(px[k], pz[k]);
            c += (unsigned)v;
        }
#pragma unroll
        for (int k = 24; k < 32; ++k) key[k] = PAD_KEY;

        // bitonic sort-32 ascending on u32 keys: CE = v_min_u32 + v_max_u32
#pragma unroll
        for (int kk = 2; kk <= 32; kk <<= 1) {
#pragma unroll
            for (int jj = kk >> 1; jj > 0; jj >>= 1) {
#pragma unroll
                for (int i = 0; i < 32; ++i) {
                    const int l = i ^ jj;
                    if (l > i) {
                        const unsigned a = key[i], b = key[l];
                        const unsigned lo = min(a, b);
                        const unsigned hi = max(a, b);
                        if ((i & kk) == 0) { key[i] = lo; key[l] = hi; }
                        else               { key[i] = hi; key[l] = lo; }
                    }
                }
            }
        }

        // streaming gather + invalid-fixup + shoelace (pads sorted to slots 24..31,
        // never touched). Invalid slots take sorted-slot-0's point -> terms telescope,
        // exactly like the reference's where(mask, pts, pts[0]).
        const float2 p0 = myp[key[0] & 31u];
        float prevx = p0.x, prevz = p0.y;
        float area2 = 0.f;
#pragma unroll
        for (int i = 1; i < 24; ++i) {
            const float2 pv = myp[key[i] & 31u];
            const bool val = key[i] < VALID_THRESH;
            const float cx2 = val ? pv.x : p0.x;
            const float cz2 = val ? pv.y : p0.y;
            area2 += prevx * cz2 - prevz * cx2;
            prevx = cx2; prevz = cz2;
        }
        area2 += prevx * p0.y - prevz * p0.x;   // closing edge
        const float area = 0.5f * fabsf(area2);

        const float hov = fmaxf(fminf(gy, qy) - fmaxf(gy - gh, qy - qh), 0.0f);
        const float inter = area * hov;
        const float va = gh * gw * gl;
        const float vb = qh * qw * ql;
        float iou = inter / (va + vb - inter + EPS_F);
        iou = fminf(fmaxf(iou, 0.0f), 1.0f);
        loss = 1.0f - iou;
    }

    // deterministic block reduction: wave shfl (width 64) + LDS
#pragma unroll
    for (int off = 32; off > 0; off >>= 1) loss += __shfl_down(loss, off, 64);
    __shared__ float wsum[4];
    const int lane = threadIdx.x & 63;
    const int wid = threadIdx.x >> 6;
    if (lane == 0) wsum[wid] = loss;
    __syncthreads();
    if (threadIdx.x == 0) {
        partial[blockIdx.x] = wsum[0] + wsum[1] + wsum[2] + wsum[3];
    }
}

__launch_bounds__(256)
__global__ void final_reduce_kernel(const float* __restrict__ partial,
                                    float* __restrict__ out,
                                    int nblocks, float invn) {
    float s = 0.f;
    for (int k = threadIdx.x; k < nblocks; k += 256) s += partial[k];
#pragma unroll
    for (int off = 32; off > 0; off >>= 1) s += __shfl_down(s, off, 64);
    __shared__ float wsum[4];
    const int lane = threadIdx.x & 63;
    const int wid = threadIdx.x >> 6;
    if (lane == 0) wsum[wid] = s;
    __syncthreads();
    if (threadIdx.x == 0) out[0] = (wsum[0] + wsum[1] + wsum[2] + wsum[3]) * invn;
}

extern "C" void kernel_launch(void* const* d_in, const int* in_sizes, int n_in,
                              void* d_out, int out_size, void* d_ws, size_t ws_size,
                              hipStream_t stream) {
    const float* g = (const float*)d_in[0];
    const float* q = (const float*)d_in[1];
    float* out = (float*)d_out;
    const int n = in_sizes[0] / 7;
    const int block = 256;
    const int nblocks = (n + block - 1) / block;   // 2048 for N=524288
    float* partial = (float*)d_ws;                 // 2048 floats = 8 KB scratch
    iou3d_loss_kernel<<<nblocks, block, 0, stream>>>(g, q, partial, n);
    final_reduce_kernel<<<1, block, 0, stream>>>(partial, out, nblocks, 1.0f / (float)n);
}

// Round 5
// 20.709 us; speedup vs baseline: 6.2097x; 1.7460x over previous
//
#include <hip/hip_runtime.h>
#include <math.h>

#define EPS_F 1e-8f

__device__ __forceinline__ float rcp_fast(float x) { return __builtin_amdgcn_rcpf(x); }

__launch_bounds__(256)
__global__ void iou3d_loss_kernel(const float* __restrict__ g,
                                  const float* __restrict__ q,
                                  float* __restrict__ partial,
                                  int n) {
    const int gid = blockIdx.x * blockDim.x + threadIdx.x;
    float loss = 0.0f;
    if (gid < n) {
        const float* gb = g + (size_t)gid * 7;
        const float* qb = q + (size_t)gid * 7;
        const float gx = gb[0], gy = gb[1], gz = gb[2], gh = gb[3], gw = gb[4], gl = gb[5], gr = gb[6];
        const float qx = qb[0], qy = qb[1], qz = qb[2], qh = qb[3], qw = qb[4], ql = qb[5], qr = qb[6];

        float sg, cg, sq_, cq;
        __sincosf(gr, &sg, &cg);
        __sincosf(qr, &sq_, &cq);

        // BEV corners in coordinates RELATIVE to (gx, gz) for conditioning.
        // Corner order (reference LX/LZ) is CW; rotation preserves orientation.
        const float LX[4] = {0.5f, 0.5f, -0.5f, -0.5f};
        const float LZ[4] = {0.5f, -0.5f, -0.5f, 0.5f};
        const float dqx = qx - gx, dqz = qz - gz;
        float ax[4], az[4], bx[4], bz[4];
#pragma unroll
        for (int k = 0; k < 4; ++k) {
            const float cxg = LX[k] * gl, czg = LZ[k] * gw;
            ax[k] =  cg * cxg + sg * czg;
            az[k] = -sg * cxg + cg * czg;
            const float cxq = LX[k] * ql, czq = LZ[k] * qw;
            bx[k] =  cq * cxq + sq_ * czq + dqx;
            bz[k] = -sq_ * cxq + cq * czq + dqz;
        }

        // Edges e_k = corner_{k+1} - corner_k and constants cross(e_k, corner_k)
        float aex[4], aez[4], acc_[4], bex[4], bez[4], bcc[4];
#pragma unroll
        for (int k = 0; k < 4; ++k) {
            aex[k] = ax[(k + 1) & 3] - ax[k];
            aez[k] = az[(k + 1) & 3] - az[k];
            acc_[k] = aex[k] * az[k] - aez[k] * ax[k];
            bex[k] = bx[(k + 1) & 3] - bx[k];
            bez[k] = bz[(k + 1) & 3] - bz[k];
            bcc[k] = bex[k] * bz[k] - bez[k] * bx[k];
        }

        // Green's theorem over the boundary of A∩B:
        //   2*Area = | Σ_{A-edges clipped by B} (t1-t0)*cross(P,d)
        //           + Σ_{B-edges clipped by A} (t1-t0)*cross(P,d) |
        // Liang–Barsky interval clip: inside(p) ⇔ cross(e, p - b1) <= 0 (CW polygons).
        float total = 0.0f;

        // A edges clipped by B
#pragma unroll
        for (int k = 0; k < 4; ++k) {
            const float Px = ax[k], Pz = az[k];
            const float dx = aex[k], dz = aez[k];
            float t0 = 0.0f, t1 = 1.0f;
#pragma unroll
            for (int h = 0; h < 4; ++h) {
                const float s  = bex[h] * dz - bez[h] * dx;          // cross(e_h, d)
                const float f0 = bex[h] * Pz - bez[h] * Px - bcc[h]; // cross(e_h, P-b1)
                const float tt = -f0 * rcp_fast(s);
                t1 = (s > 0.0f) ? fminf(t1, tt) : t1;
                t0 = (s < 0.0f) ? fmaxf(t0, tt) : t0;
                t0 = ((s == 0.0f) && (f0 > 0.0f)) ? 1e9f : t0;       // parallel & outside
            }
            total += fmaxf(t1 - t0, 0.0f) * (Px * dz - Pz * dx);
        }
        // B edges clipped by A
#pragma unroll
        for (int k = 0; k < 4; ++k) {
            const float Px = bx[k], Pz = bz[k];
            const float dx = bex[k], dz = bez[k];
            float t0 = 0.0f, t1 = 1.0f;
#pragma unroll
            for (int h = 0; h < 4; ++h) {
                const float s  = aex[h] * dz - aez[h] * dx;
                const float f0 = aex[h] * Pz - aez[h] * Px - acc_[h];
                const float tt = -f0 * rcp_fast(s);
                t1 = (s > 0.0f) ? fminf(t1, tt) : t1;
                t0 = (s < 0.0f) ? fmaxf(t0, tt) : t0;
                t0 = ((s == 0.0f) && (f0 > 0.0f)) ? 1e9f : t0;
            }
            total += fmaxf(t1 - t0, 0.0f) * (Px * dz - Pz * dx);
        }

        const float area = 0.5f * fabsf(total);

        const float hov = fmaxf(fminf(gy, qy) - fmaxf(gy - gh, qy - qh), 0.0f);
        const float inter = area * hov;
        const float va = gh * gw * gl;
        const float vb = qh * qw * ql;
        float iou = inter / (va + vb - inter + EPS_F);
        iou = fminf(fmaxf(iou, 0.0f), 1.0f);
        loss = 1.0f - iou;
    }

    // deterministic block reduction: wave shfl (width 64) + LDS
#pragma unroll
    for (int off = 32; off > 0; off >>= 1) loss += __shfl_down(loss, off, 64);
    __shared__ float wsum[4];
    const int lane = threadIdx.x & 63;
    const int wid = threadIdx.x >> 6;
    if (lane == 0) wsum[wid] = loss;
    __syncthreads();
    if (threadIdx.x == 0) {
        partial[blockIdx.x] = wsum[0] + wsum[1] + wsum[2] + wsum[3];
    }
}

__launch_bounds__(256)
__global__ void final_reduce_kernel(const float* __restrict__ partial,
                                    float* __restrict__ out,
                                    int nblocks, float invn) {
    float s = 0.f;
    for (int k = threadIdx.x; k < nblocks; k += 256) s += partial[k];
#pragma unroll
    for (int off = 32; off > 0; off >>= 1) s += __shfl_down(s, off, 64);
    __shared__ float wsum[4];
    const int lane = threadIdx.x & 63;
    const int wid = threadIdx.x >> 6;
    if (lane == 0) wsum[wid] = s;
    __syncthreads();
    if (threadIdx.x == 0) out[0] = (wsum[0] + wsum[1] + wsum[2] + wsum[3]) * invn;
}

extern "C" void kernel_launch(void* const* d_in, const int* in_sizes, int n_in,
                              void* d_out, int out_size, void* d_ws, size_t ws_size,
                              hipStream_t stream) {
    const float* g = (const float*)d_in[0];
    const float* q = (const float*)d_in[1];
    float* out = (float*)d_out;
    const int n = in_sizes[0] / 7;
    const int block = 256;
    const int nblocks = (n + block - 1) / block;   // 2048 for N=524288
    float* partial = (float*)d_ws;                 // 2048 floats = 8 KB scratch
    iou3d_loss_kernel<<<nblocks, block, 0, stream>>>(g, q, partial, n);
    final_reduce_kernel<<<1, block, 0, stream>>>(partial, out, nblocks, 1.0f / (float)n);
}

// Round 6
// 19.749 us; speedup vs baseline: 6.5114x; 1.0486x over previous
//
#include <hip/hip_runtime.h>
#include <math.h>

#define EPS_F 1e-8f

__device__ __forceinline__ float rcp_fast(float x) { return __builtin_amdgcn_rcpf(x); }

__launch_bounds__(256)
__global__ void iou3d_loss_kernel(const float* __restrict__ g,
                                  const float* __restrict__ q,
                                  float* __restrict__ partial,
                                  int n) {
    // coalesced staging: 256 boxes x 7 floats per array, loaded as float4
    __shared__ float sgb[1792];
    __shared__ float sqb[1792];
    const int tid = threadIdx.x;
    const size_t elemBase = (size_t)blockIdx.x * (256 * 7);
    const long long availll = (long long)n * 7 - (long long)elemBase;
    const int avail = (availll > 1792) ? 1792 : (int)availll;     // > 0 by grid sizing
    const int avail4 = avail >> 2;
    const float4* g4 = (const float4*)(g + elemBase);             // 7168B block stride -> 16B aligned
    const float4* q4 = (const float4*)(q + elemBase);
#pragma unroll 2
    for (int i = tid; i < avail4; i += 256) {
        ((float4*)sgb)[i] = g4[i];
        ((float4*)sqb)[i] = q4[i];
    }
    for (int i = (avail4 << 2) + tid; i < avail; i += 256) {      // tail (last block only)
        sgb[i] = g[elemBase + i];
        sqb[i] = q[elemBase + i];
    }
    __syncthreads();

    const int gid = blockIdx.x * 256 + tid;
    float loss = 0.0f;
    if (gid < n) {
        // stride-7 LDS reads: bank (7t+j) mod 32, 7 coprime 32 -> 2 lanes/bank (free)
        const float* gb = sgb + tid * 7;
        const float* qb = sqb + tid * 7;
        const float gx = gb[0], gy = gb[1], gz = gb[2], gh = gb[3], gw = gb[4], gl = gb[5], gr = gb[6];
        const float qx = qb[0], qy = qb[1], qz = qb[2], qh = qb[3], qw = qb[4], ql = qb[5], qr = qb[6];

        float sg, cg, sq_, cq;
        __sincosf(gr, &sg, &cg);
        __sincosf(qr, &sq_, &cq);

        // BEV corners relative to (gx, gz); reference corner order is CW.
        const float LX[4] = {0.5f, 0.5f, -0.5f, -0.5f};
        const float LZ[4] = {0.5f, -0.5f, -0.5f, 0.5f};
        const float dqx = qx - gx, dqz = qz - gz;
        float ax[4], az[4], bx[4], bz[4];
#pragma unroll
        for (int k = 0; k < 4; ++k) {
            const float cxg = LX[k] * gl, czg = LZ[k] * gw;
            ax[k] =  cg * cxg + sg * czg;
            az[k] = -sg * cxg + cg * czg;
            const float cxq = LX[k] * ql, czq = LZ[k] * qw;
            bx[k] =  cq * cxq + sq_ * czq + dqx;
            bz[k] = -sq_ * cxq + cq * czq + dqz;
        }

        float aex[4], aez[4], acc_[4], bex[4], bez[4], bcc[4];
#pragma unroll
        for (int k = 0; k < 4; ++k) {
            aex[k] = ax[(k + 1) & 3] - ax[k];
            aez[k] = az[(k + 1) & 3] - az[k];
            acc_[k] = aex[k] * az[k] - aez[k] * ax[k];   // cross(d, P) = -cross(P, d)
            bex[k] = bx[(k + 1) & 3] - bx[k];
            bez[k] = bz[(k + 1) & 3] - bz[k];
            bcc[k] = bex[k] * bz[k] - bez[k] * bx[k];
        }

        // shared edge-direction crosses and reciprocals:
        // A-loop (seg k clip B-edge h):  s =  sm[k][h], tt = -f0 * r[k][h]
        // B-loop (seg h clip A-edge k):  s = -sm[k][h], tt = -f0 * -r[k][h] = f0 * r[k][h]
        float sm[4][4], rr[4][4];
#pragma unroll
        for (int k = 0; k < 4; ++k)
#pragma unroll
            for (int h = 0; h < 4; ++h) {
                sm[k][h] = bex[h] * aez[k] - bez[h] * aex[k];
                rr[k][h] = rcp_fast(sm[k][h]);
            }

        // Green's theorem: 2*Area = |Σ clipped-segment (t1-t0)*cross(P,d)|,
        // Liang–Barsky clip, inside(p) ⇔ cross(e, p - v) <= 0 for CW polygons.
        float total = 0.0f;

        // A edges clipped by B
#pragma unroll
        for (int k = 0; k < 4; ++k) {
            const float Px = ax[k], Pz = az[k];
            float t0 = 0.0f, t1 = 1.0f;
#pragma unroll
            for (int h = 0; h < 4; ++h) {
                const float s  = sm[k][h];
                const float f0 = bex[h] * Pz - bez[h] * Px - bcc[h];
                const float tt = -f0 * rr[k][h];
                t1 = (s > 0.0f) ? fminf(t1, tt) : t1;
                t0 = (s < 0.0f) ? fmaxf(t0, tt) : t0;
                t0 = ((s == 0.0f) && (f0 > 0.0f)) ? 1e9f : t0;   // parallel & outside
            }
            total += fmaxf(t1 - t0, 0.0f) * (-acc_[k]);          // cross(P,d) = -acc
        }
        // B edges clipped by A
#pragma unroll
        for (int h = 0; h < 4; ++h) {
            const float Px = bx[h], Pz = bz[h];
            float t0 = 0.0f, t1 = 1.0f;
#pragma unroll
            for (int k = 0; k < 4; ++k) {
                const float s  = -sm[k][h];
                const float f0 = aex[k] * Pz - aez[k] * Px - acc_[k];
                const float tt = f0 * rr[k][h];
                t1 = (s > 0.0f) ? fminf(t1, tt) : t1;
                t0 = (s < 0.0f) ? fmaxf(t0, tt) : t0;
                t0 = ((s == 0.0f) && (f0 > 0.0f)) ? 1e9f : t0;
            }
            total += fmaxf(t1 - t0, 0.0f) * (-bcc[h]);
        }

        const float area = 0.5f * fabsf(total);

        const float hov = fmaxf(fminf(gy, qy) - fmaxf(gy - gh, qy - qh), 0.0f);
        const float inter = area * hov;
        const float va = gh * gw * gl;
        const float vb = qh * qw * ql;
        float iou = inter / (va + vb - inter + EPS_F);
        iou = fminf(fmaxf(iou, 0.0f), 1.0f);
        loss = 1.0f - iou;
    }

    // deterministic block reduction: wave shfl (width 64) + LDS
#pragma unroll
    for (int off = 32; off > 0; off >>= 1) loss += __shfl_down(loss, off, 64);
    __shared__ float wsum[4];
    const int lane = tid & 63;
    const int wid = tid >> 6;
    if (lane == 0) wsum[wid] = loss;
    __syncthreads();
    if (tid == 0) {
        partial[blockIdx.x] = wsum[0] + wsum[1] + wsum[2] + wsum[3];
    }
}

__launch_bounds__(256)
__global__ void final_reduce_kernel(const float* __restrict__ partial,
                                    float* __restrict__ out,
                                    int nblocks, float invn) {
    float s = 0.f;
    for (int k = threadIdx.x; k < nblocks; k += 256) s += partial[k];
#pragma unroll
    for (int off = 32; off > 0; off >>= 1) s += __shfl_down(s, off, 64);
    __shared__ float wsum[4];
    const int lane = threadIdx.x & 63;
    const int wid = threadIdx.x >> 6;
    if (lane == 0) wsum[wid] = s;
    __syncthreads();
    if (threadIdx.x == 0) out[0] = (wsum[0] + wsum[1] + wsum[2] + wsum[3]) * invn;
}

extern "C" void kernel_launch(void* const* d_in, const int* in_sizes, int n_in,
                              void* d_out, int out_size, void* d_ws, size_t ws_size,
                              hipStream_t stream) {
    const float* g = (const float*)d_in[0];
    const float* q = (const float*)d_in[1];
    float* out = (float*)d_out;
    const int n = in_sizes[0] / 7;
    const int block = 256;
    const int nblocks = (n + block - 1) / block;   // 2048 for N=524288
    float* partial = (float*)d_ws;                 // 2048 floats = 8 KB scratch
    iou3d_loss_kernel<<<nblocks, block, 0, stream>>>(g, q, partial, n);
    final_reduce_kernel<<<1, block, 0, stream>>>(partial, out, nblocks, 1.0f / (float)n);
}